// Round 1
// baseline (150.705 us; speedup 1.0000x reference)
//
#include <hip/hip_runtime.h>
#include <hip/hip_bf16.h>

#define N_      4096
#define D_      4096
#define H_      256
#define C_      16
#define NNZ_ATTR 262144
#define E_      131072
#define NNZ_JM  400000
#define NNZ_JA  80000
#define WORDS   128   // N_/32 words per bitmask row

// ---------------- workspace layout (bytes) ----------------
#define OFF_JM   ((size_t)0)                        // 2 MB  jm bitmask [N][WORDS]
#define OFF_ABT  ((size_t)(2u<<20))                 // 2 MB  a_aug^T bitmask [N][WORDS]
#define OFF_CNT  ((size_t)(4u<<20))                 // 16 KB row counts
#define OFF_OFF  ((size_t)((4u<<20)+(32u<<10)))     // 16 KB+4 row offsets (4097)
#define OFF_CUR  ((size_t)((4u<<20)+(64u<<10)))     // 16 KB scatter cursors
#define OFF_DINV ((size_t)((4u<<20)+(80u<<10)))     // 16 KB dinv
#define OFF_CSR  ((size_t)((4u<<20)+(96u<<10)))     // 1 MB  csr col indices
#define OFF_W1T  (OFF_CSR + (size_t)(1u<<20))       // 4 MB  W1 transposed [D][H]
#define OFF_H1   (OFF_W1T + (size_t)(4u<<20))       // 4 MB  h1 [N][H]
#define OFF_H2   (OFF_H1  + (size_t)(4u<<20))       // 256 KB h2 [N][C]
#define ZERO_BYTES ((size_t)((4u<<20)+(16u<<10)))   // jm + abt + cnt

// ---------------- kernels ----------------

__global__ void k_jm_bits(const int* __restrict__ jr, const int* __restrict__ jc,
                          unsigned* __restrict__ jm) {
    int i = blockIdx.x * 256 + threadIdx.x;
    if (i >= NNZ_JM) return;
    int p = jr[i], q = jc[i];
    atomicOr(&jm[(size_t)p * WORDS + (q >> 5)], 1u << (q & 31));
}

__global__ void k_hist(const int* __restrict__ ar, unsigned* __restrict__ cnt) {
    int i = blockIdx.x * 256 + threadIdx.x;
    if (i >= NNZ_ATTR) return;
    atomicAdd(&cnt[ar[i]], 1u);
}

// build a_aug^T bitmask: entry (p,q) of a_aug sets bit p in row q
__global__ void k_abt(const int* __restrict__ ep, const int* __restrict__ eq,
                      const int* __restrict__ jap, const int* __restrict__ jaq,
                      const unsigned* __restrict__ jm, unsigned* __restrict__ abt) {
    int i = blockIdx.x * 256 + threadIdx.x;
    if (i < E_) {
        int p = ep[i], q = eq[i];
        if ((jm[(size_t)p * WORDS + (q >> 5)] >> (q & 31)) & 1u)
            atomicOr(&abt[(size_t)q * WORDS + (p >> 5)], 1u << (p & 31));
    } else if (i < E_ + NNZ_JA) {
        int j = i - E_;
        int p = jap[j], q = jaq[j];
        atomicOr(&abt[(size_t)q * WORDS + (p >> 5)], 1u << (p & 31));
    } else if (i < E_ + NNZ_JA + N_) {
        int r = i - E_ - NNZ_JA;
        atomicOr(&abt[(size_t)r * WORDS + (r >> 5)], 1u << (r & 31));
    }
}

// exclusive scan of 4096 counts, one block of 1024 threads (4 elems each)
__global__ void k_scan(const unsigned* __restrict__ cnt, unsigned* __restrict__ off,
                       unsigned* __restrict__ cur) {
    __shared__ unsigned s[1024];
    int t = threadIdx.x;
    unsigned v0 = cnt[4*t], v1 = cnt[4*t+1], v2 = cnt[4*t+2], v3 = cnt[4*t+3];
    unsigned sum = v0 + v1 + v2 + v3;
    s[t] = sum;
    __syncthreads();
    for (int d = 1; d < 1024; d <<= 1) {
        unsigned x = 0;
        if (t >= d) x = s[t - d];
        __syncthreads();
        if (t >= d) s[t] += x;
        __syncthreads();
    }
    unsigned incl = s[t];
    unsigned o0 = incl - sum;
    unsigned o1 = o0 + v0, o2 = o1 + v1, o3 = o2 + v2;
    off[4*t] = o0; off[4*t+1] = o1; off[4*t+2] = o2; off[4*t+3] = o3;
    cur[4*t] = o0; cur[4*t+1] = o1; cur[4*t+2] = o2; cur[4*t+3] = o3;
    if (t == 1023) off[4096] = incl;
}

__global__ void k_scatter(const int* __restrict__ ar, const int* __restrict__ ac,
                          unsigned* __restrict__ cur, unsigned* __restrict__ ccol) {
    int i = blockIdx.x * 256 + threadIdx.x;
    if (i >= NNZ_ATTR) return;
    int r = ar[i];
    unsigned pos = atomicAdd(&cur[r], 1u);
    ccol[pos] = (unsigned)ac[i];
}

// W1 [H_, D_] row-major  ->  W1T [D_, H_]
__global__ void k_transpose(const float* __restrict__ in, float* __restrict__ out) {
    __shared__ float tile[32][33];
    int tx = threadIdx.x, ty = threadIdx.y;       // block (32, 8)
    int col = blockIdx.x * 32 + tx;               // D index
    #pragma unroll
    for (int j = 0; j < 4; ++j) {
        int row = blockIdx.y * 32 + ty + j * 8;   // H index
        tile[ty + j*8][tx] = in[(size_t)row * D_ + col];
    }
    __syncthreads();
    int ocol = blockIdx.y * 32 + tx;              // H index
    #pragma unroll
    for (int j = 0; j < 4; ++j) {
        int orow = blockIdx.x * 32 + ty + j * 8;  // D index
        out[(size_t)orow * H_ + ocol] = tile[tx][ty + j*8];
    }
}

// h1[r,:] = sum over csr cols c of W1T[c,:]
__global__ void k_h1(const unsigned* __restrict__ roff, const unsigned* __restrict__ ccol,
                     const float* __restrict__ w1t, float* __restrict__ h1) {
    __shared__ unsigned cols[256];
    int r = blockIdx.x, t = threadIdx.x;
    unsigned b = roff[r], e = roff[r + 1];
    float acc = 0.f;
    for (unsigned base = b; base < e; base += 256) {
        unsigned m = min(256u, e - base);
        __syncthreads();
        if ((unsigned)t < m) cols[t] = ccol[base + t];
        __syncthreads();
        unsigned i = 0;
        for (; i + 4 <= m; i += 4) {
            unsigned c0 = cols[i], c1 = cols[i+1], c2 = cols[i+2], c3 = cols[i+3];
            float a0 = w1t[(size_t)c0 * H_ + t];
            float a1 = w1t[(size_t)c1 * H_ + t];
            float a2 = w1t[(size_t)c2 * H_ + t];
            float a3 = w1t[(size_t)c3 * H_ + t];
            acc += a0; acc += a1; acc += a2; acc += a3;
        }
        for (; i < m; ++i) acc += w1t[(size_t)cols[i] * H_ + t];
    }
    h1[(size_t)r * H_ + t] = acc;
}

// dinv[q] = rsqrt(popcount(abt row q)); one wave per q, 4 waves per block
__global__ void k_dinv(const unsigned* __restrict__ abt, float* __restrict__ dinv) {
    int wid = threadIdx.x >> 6, lane = threadIdx.x & 63;
    int q = blockIdx.x * 4 + wid;
    const unsigned* row = abt + (size_t)q * WORDS;
    int c = __popc(row[lane]) + __popc(row[lane + 64]);
    for (int d = 32; d; d >>= 1) c += __shfl_down(c, d);
    if (lane == 0) dinv[q] = rsqrtf((float)c);
}

// out1[q,:] = relu(dinv[q] * sum_p bit(q,p) dinv[p] h1[p,:]) ; then h2[q,:] = out1 @ W2^T
__global__ void k_prop1(const unsigned* __restrict__ abt, const float* __restrict__ dinv,
                        const float* __restrict__ h1, const float* __restrict__ w2,
                        float* __restrict__ h2) {
    __shared__ unsigned wrow[WORDS];
    __shared__ float hrow[H_];
    __shared__ float partial[16][17];
    int q = blockIdx.x, t = threadIdx.x;    // block 256
    if (t < WORDS) wrow[t] = abt[(size_t)q * WORDS + t];
    __syncthreads();
    float acc = 0.f;
    for (int wi = 0; wi < WORDS; ++wi) {
        unsigned w = wrow[wi];
        while (w) {
            int b = __ffs(w) - 1; w &= w - 1;
            int p = wi * 32 + b;
            acc += dinv[p] * h1[(size_t)p * H_ + t];
        }
    }
    float h = fmaxf(acc * dinv[q], 0.f);
    hrow[t] = h;
    __syncthreads();
    int c = t & 15, g = t >> 4;
    float part = 0.f;
    #pragma unroll
    for (int kk = 0; kk < 16; ++kk) {
        int k = g * 16 + kk;
        part += hrow[k] * w2[(size_t)c * H_ + k];
    }
    partial[g][c] = part;
    __syncthreads();
    if (t < 16) {
        float s = 0.f;
        #pragma unroll
        for (int g2 = 0; g2 < 16; ++g2) s += partial[g2][t];
        h2[(size_t)q * C_ + t] = s;
    }
}

// out[q,c] = dinv[q] * sum_p bit(q,p) dinv[p] h2[p,c] + bias[c]
__global__ void k_prop2(const unsigned* __restrict__ abt, const float* __restrict__ dinv,
                        const float* __restrict__ h2, const float* __restrict__ bias,
                        float* __restrict__ out) {
    __shared__ unsigned wrow[WORDS];
    int q = blockIdx.x, t = threadIdx.x;    // block 128
    wrow[t] = abt[(size_t)q * WORDS + t];
    __syncthreads();
    if (t < 16) {
        float acc = 0.f;
        for (int wi = 0; wi < WORDS; ++wi) {
            unsigned w = wrow[wi];
            while (w) {
                int b = __ffs(w) - 1; w &= w - 1;
                int p = wi * 32 + b;
                acc += dinv[p] * h2[(size_t)p * C_ + t];
            }
        }
        out[(size_t)q * C_ + t] = dinv[q] * acc + bias[t];
    }
}

// ---------------- launch ----------------

extern "C" void kernel_launch(void* const* d_in, const int* in_sizes, int n_in,
                              void* d_out, int out_size, void* d_ws, size_t ws_size,
                              hipStream_t stream) {
    const int*   attr_row = (const int*)d_in[0];
    const int*   attr_col = (const int*)d_in[1];
    const int*   edge     = (const int*)d_in[2];   // [2][E_]
    const int*   jmsk     = (const int*)d_in[3];   // [2][NNZ_JM]
    const int*   jaug     = (const int*)d_in[4];   // [2][NNZ_JA]
    const float* w1       = (const float*)d_in[5]; // [H_][D_]
    const float* w2       = (const float*)d_in[6]; // [C_][H_]
    const float* bias2    = (const float*)d_in[7]; // [C_]
    float*       out      = (float*)d_out;

    char* ws = (char*)d_ws;
    unsigned* jm_bits = (unsigned*)(ws + OFF_JM);
    unsigned* abt     = (unsigned*)(ws + OFF_ABT);
    unsigned* rcnt    = (unsigned*)(ws + OFF_CNT);
    unsigned* roff    = (unsigned*)(ws + OFF_OFF);
    unsigned* rcur    = (unsigned*)(ws + OFF_CUR);
    float*    dinv    = (float*)   (ws + OFF_DINV);
    unsigned* ccol    = (unsigned*)(ws + OFF_CSR);
    float*    w1t     = (float*)   (ws + OFF_W1T);
    float*    h1      = (float*)   (ws + OFF_H1);
    float*    h2      = (float*)   (ws + OFF_H2);

    hipMemsetAsync(d_ws, 0, ZERO_BYTES, stream);

    k_jm_bits<<<(NNZ_JM + 255) / 256, 256, 0, stream>>>(jmsk, jmsk + NNZ_JM, jm_bits);
    k_hist<<<(NNZ_ATTR + 255) / 256, 256, 0, stream>>>(attr_row, rcnt);
    k_abt<<<(E_ + NNZ_JA + N_ + 255) / 256, 256, 0, stream>>>(
        edge, edge + E_, jaug, jaug + NNZ_JA, jm_bits, abt);
    k_scan<<<1, 1024, 0, stream>>>(rcnt, roff, rcur);
    k_scatter<<<(NNZ_ATTR + 255) / 256, 256, 0, stream>>>(attr_row, attr_col, rcur, ccol);
    k_transpose<<<dim3(D_ / 32, H_ / 32), dim3(32, 8), 0, stream>>>(w1, w1t);
    k_h1<<<N_, 256, 0, stream>>>(roff, ccol, w1t, h1);
    k_dinv<<<N_ / 4, 256, 0, stream>>>(abt, dinv);
    k_prop1<<<N_, 256, 0, stream>>>(abt, dinv, h1, w2, h2);
    k_prop2<<<N_, 128, 0, stream>>>(abt, dinv, h2, bias2, out);
}